// Round 14
// baseline (150.725 us; speedup 1.0000x reference)
//
#include <hip/hip_runtime.h>

#define NB   4
#define H_IN 14
#define W_IN 14
#define FIN  32
#define DI   8
#define F    32
#define C    288   // 3*3*32
#define DO   16
#define HO   12
#define WO   12
#define NPOS (NB*HO*WO)   // 576
#define EPS  1e-7f

#define CH   16            // c-chunks
#define CC   (C/CH)        // 18

#define XELE  (NB*H_IN*W_IN*FIN*DI)            // 200,704
#define W2H_BYTES  ((size_t)F*C*DO*DI*2)       // 2,359,296
#define XH_BYTES   ((size_t)XELE*2)            // 401,408
#define CENT_BYTES ((size_t)NPOS*F*DO*4)       // 1,179,648
#define PART_BYTES ((size_t)CH*CENT_BYTES)     // 18,874,368 (part1; part2 aliases)
#define OUT1_BYTES CENT_BYTES

typedef _Float16 h2 __attribute__((ext_vector_type(2)));

__device__ __forceinline__ unsigned int pack2(float a, float b) {
    h2 v; v.x = (_Float16)a; v.y = (_Float16)b;
    return __builtin_bit_cast(unsigned int, v);
}

// 8-term fp16 dot with fp32 accumulate
__device__ __forceinline__ float dot8h(const uint4 w, const uint4 v, float acc) {
#if __has_builtin(__builtin_amdgcn_fdot2)
    acc = __builtin_amdgcn_fdot2(__builtin_bit_cast(h2, w.x), __builtin_bit_cast(h2, v.x), acc, false);
    acc = __builtin_amdgcn_fdot2(__builtin_bit_cast(h2, w.y), __builtin_bit_cast(h2, v.y), acc, false);
    acc = __builtin_amdgcn_fdot2(__builtin_bit_cast(h2, w.z), __builtin_bit_cast(h2, v.z), acc, false);
    acc = __builtin_amdgcn_fdot2(__builtin_bit_cast(h2, w.w), __builtin_bit_cast(h2, v.w), acc, false);
#else
    const h2 w0 = __builtin_bit_cast(h2, w.x), v0 = __builtin_bit_cast(h2, v.x);
    const h2 w1 = __builtin_bit_cast(h2, w.y), v1 = __builtin_bit_cast(h2, v.y);
    const h2 w2 = __builtin_bit_cast(h2, w.z), v2 = __builtin_bit_cast(h2, v.z);
    const h2 w3 = __builtin_bit_cast(h2, w.w), v3 = __builtin_bit_cast(h2, v.w);
    acc += (float)w0.x*(float)v0.x + (float)w0.y*(float)v0.y
         + (float)w1.x*(float)v1.x + (float)w1.y*(float)v1.y
         + (float)w2.x*(float)v2.x + (float)w2.y*(float)v2.y
         + (float)w3.x*(float)v3.x + (float)w3.y*(float)v3.y;
#endif
    return acc;
}

__device__ __forceinline__ int xbase_of(int pos) {
    const int b = pos/(HO*WO), rem = pos%(HO*WO), ho = rem/WO, wo = rem%WO;
    return ((b*H_IN + ho)*W_IN + wo)*FIN*DI;
}

// stage xs4[cl][p] = 8 halves of x for (c, pos) — 144 uint4 = 2.3 KB
__device__ __forceinline__ void stage_xh(const unsigned short* __restrict__ xh,
                                         uint4 (*xs4)[8],
                                         const int ch, const int pg, const int tid) {
    if (tid < CC*8) {
        const int cl = tid >> 3, p = tid & 7;
        const int c  = ch*CC + cl;
        const int slab = c >> 5, fin = c & 31;
        const int kh = slab/3, kw = slab%3;
        const int off = xbase_of(pg*8 + p) + (kh*W_IN + kw)*FIN*DI + fin*DI;
        xs4[cl][p] = *(const uint4*)(xh + off);
    }
}

// ---- fused conversion: W[f][c][o][i] fp32 -> W2h[c][o][f][i] fp16, x -> xh ----
__global__ __launch_bounds__(256) void kernConv(const float* __restrict__ Wt,
                                                unsigned short* __restrict__ W2h,
                                                const float* __restrict__ x,
                                                unsigned short* __restrict__ xh) {
    const int b = blockIdx.x;
    if (b < (F*C*DO)/256) {     // 576 W-blocks
        const int idx = b*256 + threadIdx.x;   // (c*DO+o)*F+f
        const int f = idx & 31, o = (idx >> 5) & 15, c = idx >> 9;
        const float* src = Wt + ((size_t)(f*C + c)*DO + o)*DI;
        const float4 a = *(const float4*)src;
        const float4 bb = *(const float4*)(src + 4);
        uint4 r;
        r.x = pack2(a.x, a.y);  r.y = pack2(a.z, a.w);
        r.z = pack2(bb.x, bb.y); r.w = pack2(bb.z, bb.w);
        ((uint4*)W2h)[idx] = r;
    } else {                    // 196 x-blocks
        const int i = (b - (F*C*DO)/256)*256 + threadIdx.x;
        if (i < XELE/4) {
            const float4 v = ((const float4*)x)[i];
            uint2 o;
            o.x = pack2(v.x, v.y); o.y = pack2(v.z, v.w);
            ((uint2*)xh)[i] = o;
        }
    }
}

// ---- kern1: cent1 partials. thread=(f, o-pair), 8 positions. fp16 dots. -------
// writes part1[ch][pos][o][f] fp32  (R13-proven, untouched)
__global__ __launch_bounds__(256, 4) void kern1n(const unsigned short* __restrict__ xh,
                                                 const unsigned short* __restrict__ W2h,
                                                 float* __restrict__ part1)
{
    __shared__ uint4 xs4[CC][8];
    const int tid = threadIdx.x;
    const int f  = tid & 31;
    const int og = tid >> 5;          // 0..7
    const int o0 = 2*og, o1 = o0 + 1;
    const int ch = blockIdx.x & (CH-1);
    const int pg = blockIdx.x >> 4;   // 0..71

    stage_xh(xh, xs4, ch, pg, tid);
    __syncthreads();

    const uint4* W2h4 = (const uint4*)W2h;
    const int c0 = ch*CC;

    float acc0[8], acc1[8];
    #pragma unroll
    for (int p = 0; p < 8; ++p) { acc0[p] = 0.f; acc1[p] = 0.f; }

    #pragma unroll 1
    for (int cl = 0; cl < CC; ++cl) {
        const int c = c0 + cl;
        const uint4 w0 = W2h4[(size_t)(c*DO + o0)*F + f];
        const uint4 w1 = W2h4[(size_t)(c*DO + o1)*F + f];
        #pragma unroll
        for (int p = 0; p < 8; ++p) {
            const uint4 xv = xs4[cl][p];
            acc0[p] = dot8h(w0, xv, acc0[p]);
            acc1[p] = dot8h(w1, xv, acc1[p]);
        }
    }
    #pragma unroll
    for (int p = 0; p < 8; ++p) {
        const size_t base = ((size_t)(ch*NPOS + pg*8 + p))*DO;
        part1[(base + o0)*F + f] = acc0[p];
        part1[(base + o1)*F + f] = acc1[p];
    }
}

// ---- kernO: out1[pos][f][o] = squash(sum_ch part1 / 32). ----------------------
__global__ __launch_bounds__(512) void kernO(const float* __restrict__ part1,
                                             float* __restrict__ out1)
{
    __shared__ float red[512];
    const int pos = blockIdx.x, tid = threadIdx.x;
    const int f = tid & 31, o = tid >> 5;

    float s = 0.f;
    #pragma unroll
    for (int k = 0; k < CH; ++k)
        s += part1[(size_t)(k*NPOS + pos)*512 + tid];
    s *= (1.f/32.f);

    red[tid] = s*s;
    __syncthreads();
    if (tid < 256) red[tid] += red[tid + 256];
    __syncthreads();
    if (tid < 128) red[tid] += red[tid + 128];
    __syncthreads();
    if (tid < 64)  red[tid] += red[tid + 64];
    __syncthreads();
    if (tid < 32) {
        const float sn = red[tid] + red[tid + 32];
        red[tid] = (sn/(1.f + sn)) * rsqrtf(sn + EPS);
    }
    __syncthreads();
    out1[(size_t)pos*512 + f*DO + o] = s * red[f];
}

// ---- kern2: thread=(f, pos); all 16 o in-thread; softmax = in-wave shuffle. ---
// ZERO barriers in the c-loop. writes part2[ch][pos][f][o] fp32 (aliases part1).
__global__ __launch_bounds__(256) void kern2n(const unsigned short* __restrict__ xh,
                                              const unsigned short* __restrict__ W2h,
                                              const float* __restrict__ out1,
                                              float* __restrict__ part2)
{
    __shared__ uint4 xs4[CC][8];        // 2.3 KB
    const int tid = threadIdx.x;
    const int f  = tid & 31;
    const int pp = tid >> 5;            // 0..7
    const int ch = blockIdx.x & (CH-1);
    const int pg = blockIdx.x >> 4;     // 0..71
    const int pos = pg*8 + pp;

    stage_xh(xh, xs4, ch, pg, tid);

    float o1[DO];
    {
        const float4* s = (const float4*)(out1 + (size_t)pos*512 + f*DO);
        #pragma unroll
        for (int q = 0; q < 4; ++q) {
            const float4 v = s[q];
            o1[4*q+0] = v.x; o1[4*q+1] = v.y; o1[4*q+2] = v.z; o1[4*q+3] = v.w;
        }
    }
    __syncthreads();

    const uint4* W2h4 = (const uint4*)W2h;
    const int c0 = ch*CC;

    float acc[DO];
    #pragma unroll
    for (int o = 0; o < DO; ++o) acc[o] = 0.f;

    #pragma unroll 1
    for (int cl = 0; cl < CC; ++cl) {
        const int c = c0 + cl;
        const uint4 xv = xs4[cl][pp];
        const uint4* wb = W2h4 + (size_t)c*DO*F + f;

        float pred[DO];
        {   // o = 0..7: batch 8 loads then 32 dot2
            uint4 w[8];
            #pragma unroll
            for (int o = 0; o < 8; ++o) w[o] = wb[o*F];
            #pragma unroll
            for (int o = 0; o < 8; ++o) pred[o] = dot8h(w[o], xv, 0.f);
        }
        {   // o = 8..15
            uint4 w[8];
            #pragma unroll
            for (int o = 0; o < 8; ++o) w[o] = wb[(o+8)*F];
            #pragma unroll
            for (int o = 0; o < 8; ++o) pred[8+o] = dot8h(w[o], xv, 0.f);
        }

        float agr = 0.f;
        #pragma unroll
        for (int o = 0; o < DO; ++o) agr += pred[o]*o1[o];

        // softmax over the 32 f-lanes (masks <32 stay within each half-wave)
        float m = agr;
        m = fmaxf(m, __shfl_xor(m, 1));
        m = fmaxf(m, __shfl_xor(m, 2));
        m = fmaxf(m, __shfl_xor(m, 4));
        m = fmaxf(m, __shfl_xor(m, 8));
        m = fmaxf(m, __shfl_xor(m, 16));
        const float e = __expf(agr - m);
        float s = e;
        s += __shfl_xor(s, 1);
        s += __shfl_xor(s, 2);
        s += __shfl_xor(s, 4);
        s += __shfl_xor(s, 8);
        s += __shfl_xor(s, 16);
        const float cc = e / s;

        #pragma unroll
        for (int o = 0; o < DO; ++o) acc[o] += cc*pred[o];
    }

    float4* d = (float4*)(part2 + ((size_t)(ch*NPOS + pos)*F + f)*DO);
    d[0] = make_float4(acc[0],  acc[1],  acc[2],  acc[3]);
    d[1] = make_float4(acc[4],  acc[5],  acc[6],  acc[7]);
    d[2] = make_float4(acc[8],  acc[9],  acc[10], acc[11]);
    d[3] = make_float4(acc[12], acc[13], acc[14], acc[15]);
}

// ---- kern3: reduce cent2 partials ([ch][pos][f][o]), squash, store. -----------
__global__ __launch_bounds__(256) void kern3(const float* __restrict__ part2,
                                             float* __restrict__ out)
{
    const int tid = threadIdx.x;
    const int f = tid & 31, p = tid >> 5;
    const int pos = blockIdx.x*8 + p;

    float cent[DO];
    #pragma unroll
    for (int o = 0; o < DO; ++o) cent[o] = 0.f;
    #pragma unroll
    for (int k = 0; k < CH; ++k) {
        const float4* s = (const float4*)(part2 + ((size_t)(k*NPOS + pos)*F + f)*DO);
        #pragma unroll
        for (int q = 0; q < 4; ++q) {
            const float4 v = s[q];
            cent[q*4+0] += v.x; cent[q*4+1] += v.y;
            cent[q*4+2] += v.z; cent[q*4+3] += v.w;
        }
    }
    float sn = 0.f;
    #pragma unroll
    for (int o = 0; o < DO; ++o) sn += cent[o]*cent[o];
    const float sc = (sn/(1.f + sn)) * rsqrtf(sn + EPS);
    float4* dst = (float4*)(out + ((size_t)pos*F + f)*DO);
    dst[0] = make_float4(cent[0]*sc,  cent[1]*sc,  cent[2]*sc,  cent[3]*sc);
    dst[1] = make_float4(cent[4]*sc,  cent[5]*sc,  cent[6]*sc,  cent[7]*sc);
    dst[2] = make_float4(cent[8]*sc,  cent[9]*sc,  cent[10]*sc, cent[11]*sc);
    dst[3] = make_float4(cent[12]*sc, cent[13]*sc, cent[14]*sc, cent[15]*sc);
}

// -------- fp32 single-kernel fallback (if ws too small) ------------------------
__device__ __forceinline__ float dot8(const float4* __restrict__ w,
                                      const float4 p0, const float4 p1) {
    float4 a = w[0], b = w[1];
    return a.x*p0.x + a.y*p0.y + a.z*p0.z + a.w*p0.w
         + b.x*p1.x + b.y*p1.y + b.z*p1.z + b.w*p1.w;
}

__global__ __launch_bounds__(256) void capsule_kernel_f32(
    const float* __restrict__ x, const float* __restrict__ Wt,
    float* __restrict__ out)
{
    __shared__ float patch[C*DI];
    __shared__ float cent[F*DO];
    __shared__ float out1[F*DO];
    __shared__ float agr[F*C];
    __shared__ float scale_s[F];

    const int tid = threadIdx.x;
    const int pos = blockIdx.x;
    const int b   = pos / (HO*WO);
    const int rem = pos % (HO*WO);
    const int ho  = rem / WO;
    const int wo  = rem % WO;

    #pragma unroll
    for (int slab = 0; slab < 9; ++slab) {
        const int kh = slab / 3, kw = slab % 3;
        const float* src = x + (((b*H_IN + ho + kh)*W_IN + (wo + kw))*FIN)*DI;
        patch[slab*256 + tid] = src[tid];
    }
    __syncthreads();

    const float4* pv = (const float4*)patch;

    {
        const int fo0 = tid, fo1 = tid + 256;
        const int f0 = fo0 >> 4, o0 = fo0 & 15;
        const int f1 = fo1 >> 4, o1 = fo1 & 15;
        float acc0 = 0.f, acc1 = 0.f;
        for (int c = 0; c < C; ++c) {
            const float4 p0 = pv[c*2], p1 = pv[c*2+1];
            acc0 += dot8((const float4*)(Wt + ((f0*C + c)*DO + o0)*DI), p0, p1);
            acc1 += dot8((const float4*)(Wt + ((f1*C + c)*DO + o1)*DI), p0, p1);
        }
        cent[fo0] = acc0 * (1.f/32.f);
        cent[fo1] = acc1 * (1.f/32.f);
    }
    __syncthreads();

    if (tid < F) {
        float sn = 0.f;
        #pragma unroll
        for (int o = 0; o < DO; ++o) { float v = cent[tid*DO + o]; sn += v*v; }
        const float sc = (sn/(1.f + sn)) * rsqrtf(sn + EPS);
        #pragma unroll
        for (int o = 0; o < DO; ++o) out1[tid*DO + o] = cent[tid*DO + o] * sc;
    }
    __syncthreads();

    #pragma unroll 1
    for (int r = 0; r < (F*C)/256; ++r) {
        const int pp = tid + 256*r;
        const int f = pp / C, c = pp % C;
        const float4* wrow = (const float4*)(Wt + (f*C + c)*DO*DI);
        const float4 p0 = pv[c*2], p1 = pv[c*2+1];
        float a = 0.f;
        #pragma unroll
        for (int o = 0; o < DO; ++o) a += dot8(wrow + o*2, p0, p1) * out1[f*DO + o];
        agr[pp] = a;
    }
    __syncthreads();

    for (int c = tid; c < C; c += 256) {
        float m = -1e30f;
        #pragma unroll
        for (int f = 0; f < F; ++f) m = fmaxf(m, agr[f*C + c]);
        float s = 0.f;
        #pragma unroll
        for (int f = 0; f < F; ++f) {
            const float e = __expf(agr[f*C + c] - m);
            agr[f*C + c] = e; s += e;
        }
        const float inv = 1.f / s;
        #pragma unroll
        for (int f = 0; f < F; ++f) agr[f*C + c] *= inv;
    }
    __syncthreads();

    {
        const int fo0 = tid, fo1 = tid + 256;
        const int f0 = fo0 >> 4, o0 = fo0 & 15;
        const int f1 = fo1 >> 4, o1 = fo1 & 15;
        float acc0 = 0.f, acc1 = 0.f;
        for (int c = 0; c < C; ++c) {
            const float4 p0 = pv[c*2], p1 = pv[c*2+1];
            acc0 += agr[f0*C + c] * dot8((const float4*)(Wt + ((f0*C + c)*DO + o0)*DI), p0, p1);
            acc1 += agr[f1*C + c] * dot8((const float4*)(Wt + ((f1*C + c)*DO + o1)*DI), p0, p1);
        }
        cent[fo0] = acc0;
        cent[fo1] = acc1;
    }
    __syncthreads();

    if (tid < F) {
        float sn = 0.f;
        #pragma unroll
        for (int o = 0; o < DO; ++o) { float v = cent[tid*DO + o]; sn += v*v; }
        scale_s[tid] = (sn/(1.f + sn)) * rsqrtf(sn + EPS);
    }
    __syncthreads();

    out[pos*(F*DO) + tid]       = cent[tid]       * scale_s[tid >> 4];
    out[pos*(F*DO) + tid + 256] = cent[tid + 256] * scale_s[(tid >> 4) + 16];
}

extern "C" void kernel_launch(void* const* d_in, const int* in_sizes, int n_in,
                              void* d_out, int out_size, void* d_ws, size_t ws_size,
                              hipStream_t stream) {
    const float* x  = (const float*)d_in[0];
    const float* Wt = (const float*)d_in[1];
    float* out = (float*)d_out;

    if (ws_size >= W2H_BYTES + XH_BYTES + PART_BYTES + OUT1_BYTES) {
        unsigned short* W2h = (unsigned short*)d_ws;
        unsigned short* xh  = (unsigned short*)((char*)d_ws + W2H_BYTES);
        float* part1 = (float*)((char*)d_ws + W2H_BYTES + XH_BYTES);   // part2 aliases
        float* out1  = (float*)((char*)d_ws + W2H_BYTES + XH_BYTES + PART_BYTES);
        kernConv<<<(F*C*DO)/256 + XELE/4/256, 256, 0, stream>>>(Wt, W2h, x, xh); // 772
        kern1n<<<CH*(NPOS/8), 256, 0, stream>>>(xh, W2h, part1);       // 1152 blocks
        kernO<<<NPOS, 512, 0, stream>>>(part1, out1);                  // 576 blocks
        kern2n<<<CH*(NPOS/8), 256, 0, stream>>>(xh, W2h, out1, part1); // 1152 blocks
        kern3<<<NPOS/8, 256, 0, stream>>>(part1, out);                 // 72 blocks
    } else {
        capsule_kernel_f32<<<NPOS, 256, 0, stream>>>(x, Wt, out);
    }
}

// Round 15
// 142.734 us; speedup vs baseline: 1.0560x; 1.0560x over previous
//
#include <hip/hip_runtime.h>

#define NB   4
#define H_IN 14
#define W_IN 14
#define FIN  32
#define DI   8
#define F    32
#define C    288   // 3*3*32
#define DO   16
#define HO   12
#define WO   12
#define NPOS (NB*HO*WO)   // 576
#define EPS  1e-7f

#define CH   16            // c-chunks
#define CC   (C/CH)        // 18

#define XELE  (NB*H_IN*W_IN*FIN*DI)            // 200,704
#define W2H_BYTES  ((size_t)F*C*DO*DI*2)       // 2,359,296
#define XH_BYTES   ((size_t)XELE*2)            // 401,408
#define CENT_BYTES ((size_t)NPOS*F*DO*4)       // 1,179,648
#define PART_BYTES ((size_t)CH*CENT_BYTES)     // 18,874,368 (part1; part2 aliases)
#define OUT1_BYTES CENT_BYTES

typedef _Float16 h2 __attribute__((ext_vector_type(2)));

__device__ __forceinline__ unsigned int pack2(float a, float b) {
    h2 v; v.x = (_Float16)a; v.y = (_Float16)b;
    return __builtin_bit_cast(unsigned int, v);
}

// 8-term fp16 dot with fp32 accumulate
__device__ __forceinline__ float dot8h(const uint4 w, const uint4 v, float acc) {
#if __has_builtin(__builtin_amdgcn_fdot2)
    acc = __builtin_amdgcn_fdot2(__builtin_bit_cast(h2, w.x), __builtin_bit_cast(h2, v.x), acc, false);
    acc = __builtin_amdgcn_fdot2(__builtin_bit_cast(h2, w.y), __builtin_bit_cast(h2, v.y), acc, false);
    acc = __builtin_amdgcn_fdot2(__builtin_bit_cast(h2, w.z), __builtin_bit_cast(h2, v.z), acc, false);
    acc = __builtin_amdgcn_fdot2(__builtin_bit_cast(h2, w.w), __builtin_bit_cast(h2, v.w), acc, false);
#else
    const h2 w0 = __builtin_bit_cast(h2, w.x), v0 = __builtin_bit_cast(h2, v.x);
    const h2 w1 = __builtin_bit_cast(h2, w.y), v1 = __builtin_bit_cast(h2, v.y);
    const h2 w2 = __builtin_bit_cast(h2, w.z), v2 = __builtin_bit_cast(h2, v.z);
    const h2 w3 = __builtin_bit_cast(h2, w.w), v3 = __builtin_bit_cast(h2, v.w);
    acc += (float)w0.x*(float)v0.x + (float)w0.y*(float)v0.y
         + (float)w1.x*(float)v1.x + (float)w1.y*(float)v1.y
         + (float)w2.x*(float)v2.x + (float)w2.y*(float)v2.y
         + (float)w3.x*(float)v3.x + (float)w3.y*(float)v3.y;
#endif
    return acc;
}

__device__ __forceinline__ int xbase_of(int pos) {
    const int b = pos/(HO*WO), rem = pos%(HO*WO), ho = rem/WO, wo = rem%WO;
    return ((b*H_IN + ho)*W_IN + wo)*FIN*DI;
}

__device__ __forceinline__ int coff_of(int c) {
    const int slab = c >> 5, fin = c & 31;
    const int kh = slab/3, kw = slab%3;
    return (kh*W_IN + kw)*FIN*DI + fin*DI;
}

// ---- fused conversion: W[f][c][o][i] fp32 -> W2h[c][o][f][i] fp16, x -> xh ----
__global__ __launch_bounds__(256) void kernConv(const float* __restrict__ Wt,
                                                unsigned short* __restrict__ W2h,
                                                const float* __restrict__ x,
                                                unsigned short* __restrict__ xh) {
    const int b = blockIdx.x;
    if (b < (F*C*DO)/256) {     // 576 W-blocks
        const int idx = b*256 + threadIdx.x;   // (c*DO+o)*F+f
        const int f = idx & 31, o = (idx >> 5) & 15, c = idx >> 9;
        const float* src = Wt + ((size_t)(f*C + c)*DO + o)*DI;
        const float4 a = *(const float4*)src;
        const float4 bb = *(const float4*)(src + 4);
        uint4 r;
        r.x = pack2(a.x, a.y);  r.y = pack2(a.z, a.w);
        r.z = pack2(bb.x, bb.y); r.w = pack2(bb.z, bb.w);
        ((uint4*)W2h)[idx] = r;
    } else {                    // 196 x-blocks
        const int i = (b - (F*C*DO)/256)*256 + threadIdx.x;
        if (i < XELE/4) {
            const float4 v = ((const float4*)x)[i];
            uint2 o;
            o.x = pack2(v.x, v.y); o.y = pack2(v.z, v.w);
            ((uint2*)xh)[i] = o;
        }
    }
}

// ---- kern1: cent1 partials. thread=(f, o-pair); x via wave-uniform (scalar)
// loads; NO LDS, NO barriers. writes part1[ch][pos][o][f] fp32
__global__ __launch_bounds__(256, 4) void kern1n(const unsigned short* __restrict__ xh,
                                                 const unsigned short* __restrict__ W2h,
                                                 float* __restrict__ part1)
{
    const int tid = threadIdx.x;
    const int f  = tid & 31;
    const int og = tid >> 5;          // 0..7
    const int o0 = 2*og, o1 = o0 + 1;
    const int ch = blockIdx.x & (CH-1);
    const int pg = blockIdx.x >> 4;   // 0..71

    int xoff[8];                      // block-uniform -> SGPRs
    #pragma unroll
    for (int p = 0; p < 8; ++p) xoff[p] = xbase_of(pg*8 + p);

    const uint4* W2h4 = (const uint4*)W2h;
    const int c0 = ch*CC;

    float acc0[8], acc1[8];
    #pragma unroll
    for (int p = 0; p < 8; ++p) { acc0[p] = 0.f; acc1[p] = 0.f; }

    #pragma unroll 1
    for (int cl = 0; cl < CC; ++cl) {
        const int c = c0 + cl;
        const int coff = coff_of(c);
        const uint4 w0 = W2h4[(size_t)(c*DO + o0)*F + f];
        const uint4 w1 = W2h4[(size_t)(c*DO + o1)*F + f];
        #pragma unroll
        for (int p = 0; p < 8; ++p) {
            const uint4 xv = *(const uint4*)(xh + xoff[p] + coff);  // uniform
            acc0[p] = dot8h(w0, xv, acc0[p]);
            acc1[p] = dot8h(w1, xv, acc1[p]);
        }
    }
    #pragma unroll
    for (int p = 0; p < 8; ++p) {
        const size_t base = ((size_t)(ch*NPOS + pg*8 + p))*DO;
        part1[(base + o0)*F + f] = acc0[p];
        part1[(base + o1)*F + f] = acc1[p];
    }
}

// ---- kernO: out1[pos][f][o] = squash(sum_ch part1 / 32). ----------------------
__global__ __launch_bounds__(512) void kernO(const float* __restrict__ part1,
                                             float* __restrict__ out1)
{
    __shared__ float red[512];
    const int pos = blockIdx.x, tid = threadIdx.x;
    const int f = tid & 31, o = tid >> 5;

    float s = 0.f;
    #pragma unroll
    for (int k = 0; k < CH; ++k)
        s += part1[(size_t)(k*NPOS + pos)*512 + tid];
    s *= (1.f/32.f);

    red[tid] = s*s;
    __syncthreads();
    if (tid < 256) red[tid] += red[tid + 256];
    __syncthreads();
    if (tid < 128) red[tid] += red[tid + 128];
    __syncthreads();
    if (tid < 64)  red[tid] += red[tid + 64];
    __syncthreads();
    if (tid < 32) {
        const float sn = red[tid] + red[tid + 32];
        red[tid] = (sn/(1.f + sn)) * rsqrtf(sn + EPS);
    }
    __syncthreads();
    out1[(size_t)pos*512 + f*DO + o] = s * red[f];
}

// ---- kern2: thread=(f, o-pair); x via scalar loads; softmax via LDS (R13). ----
// writes part2[ch][pos][o][f] fp32 (aliases part1)
__global__ __launch_bounds__(256) void kern2n(const unsigned short* __restrict__ xh,
                                              const unsigned short* __restrict__ W2h,
                                              const float* __restrict__ out1,
                                              float* __restrict__ part2)
{
    __shared__ float red[2][4][8][32];  // 8 KB (dbuf)
    __shared__ float ccs[2][8][32];     // 2 KB (dbuf)

    const int tid = threadIdx.x;
    const int f  = tid & 31;
    const int og = tid >> 5;            // 0..7
    const int o0 = 2*og, o1 = o0 + 1;
    const int wv = tid >> 6;            // wave 0..3
    const int half = (tid >> 5) & 1;    // og parity within wave
    const int ch = blockIdx.x & (CH-1);
    const int pg = blockIdx.x >> 4;     // 0..71

    int xoff[8];                        // block-uniform -> SGPRs
    #pragma unroll
    for (int p = 0; p < 8; ++p) xoff[p] = xbase_of(pg*8 + p);

    // out1 values for (f, o0/o1) per position
    float u0[8], u1[8];
    #pragma unroll
    for (int p = 0; p < 8; ++p) {
        const float* up = out1 + (size_t)(pg*8 + p)*512 + f*DO;
        u0[p] = up[o0];
        u1[p] = up[o1];
    }

    const uint4* W2h4 = (const uint4*)W2h;
    const int c0 = ch*CC;

    float acc0[8], acc1[8];
    #pragma unroll
    for (int p = 0; p < 8; ++p) { acc0[p] = 0.f; acc1[p] = 0.f; }

    #pragma unroll 1
    for (int cl = 0; cl < CC; ++cl) {
        const int c = c0 + cl;
        const int buf = cl & 1;
        const int coff = coff_of(c);
        const uint4 w0 = W2h4[(size_t)(c*DO + o0)*F + f];
        const uint4 w1 = W2h4[(size_t)(c*DO + o1)*F + f];

        float pred0[8], pred1[8];
        #pragma unroll
        for (int p = 0; p < 8; ++p) {
            const uint4 xv = *(const uint4*)(xh + xoff[p] + coff);  // uniform
            pred0[p] = dot8h(w0, xv, 0.f);
            pred1[p] = dot8h(w1, xv, 0.f);
        }

        // agr partial over this thread's two o's; combine og-pairs via xor-32
        #pragma unroll
        for (int p = 0; p < 8; ++p) {
            float ap = pred0[p]*u0[p] + pred1[p]*u1[p];
            ap += __shfl_xor(ap, 32);
            if (half == 0) red[buf][wv][p][f] = ap;
        }
        __syncthreads();

        // remapped role: (p2, f2); finish f-sum, softmax over f, publish cc
        {
            const int p2 = tid >> 5, f2 = tid & 31;
            const float agr = red[buf][0][p2][f2] + red[buf][1][p2][f2]
                            + red[buf][2][p2][f2] + red[buf][3][p2][f2];
            float m = agr;
            m = fmaxf(m, __shfl_xor(m, 1));
            m = fmaxf(m, __shfl_xor(m, 2));
            m = fmaxf(m, __shfl_xor(m, 4));
            m = fmaxf(m, __shfl_xor(m, 8));
            m = fmaxf(m, __shfl_xor(m, 16));
            const float e = __expf(agr - m);
            float s = e;
            s += __shfl_xor(s, 1);
            s += __shfl_xor(s, 2);
            s += __shfl_xor(s, 4);
            s += __shfl_xor(s, 8);
            s += __shfl_xor(s, 16);
            ccs[buf][p2][f2] = e / s;
        }
        __syncthreads();

        // back to (f, og): accumulate cent2
        #pragma unroll
        for (int p = 0; p < 8; ++p) {
            const float cv = ccs[buf][p][f];
            acc0[p] += cv*pred0[p];
            acc1[p] += cv*pred1[p];
        }
    }

    #pragma unroll
    for (int p = 0; p < 8; ++p) {
        const size_t base = ((size_t)(ch*NPOS + pg*8 + p))*DO;
        part2[(base + o0)*F + f] = acc0[p];
        part2[(base + o1)*F + f] = acc1[p];
    }
}

// ---- kern3: reduce cent2 partials ([ch][pos][o][f]), squash, store. -----------
__global__ __launch_bounds__(256) void kern3(const float* __restrict__ part2,
                                             float* __restrict__ out)
{
    const int tid = threadIdx.x;
    const int f = tid & 31, p = tid >> 5;
    const int pos = blockIdx.x*8 + p;

    float cent[DO];
    #pragma unroll
    for (int o = 0; o < DO; ++o) cent[o] = 0.f;
    #pragma unroll 1
    for (int k = 0; k < CH; ++k) {
        const float* s = part2 + (size_t)(k*NPOS + pos)*512 + f;
        #pragma unroll
        for (int o = 0; o < DO; ++o) cent[o] += s[o*F];
    }
    float sn = 0.f;
    #pragma unroll
    for (int o = 0; o < DO; ++o) sn += cent[o]*cent[o];
    const float sc = (sn/(1.f + sn)) * rsqrtf(sn + EPS);
    float* dst = out + ((size_t)pos*F + f)*DO;
    #pragma unroll
    for (int o = 0; o < DO; ++o) dst[o] = cent[o]*sc;
}

// -------- fp32 single-kernel fallback (if ws too small) ------------------------
__device__ __forceinline__ float dot8(const float4* __restrict__ w,
                                      const float4 p0, const float4 p1) {
    float4 a = w[0], b = w[1];
    return a.x*p0.x + a.y*p0.y + a.z*p0.z + a.w*p0.w
         + b.x*p1.x + b.y*p1.y + b.z*p1.z + b.w*p1.w;
}

__global__ __launch_bounds__(256) void capsule_kernel_f32(
    const float* __restrict__ x, const float* __restrict__ Wt,
    float* __restrict__ out)
{
    __shared__ float patch[C*DI];
    __shared__ float cent[F*DO];
    __shared__ float out1[F*DO];
    __shared__ float agr[F*C];
    __shared__ float scale_s[F];

    const int tid = threadIdx.x;
    const int pos = blockIdx.x;
    const int b   = pos / (HO*WO);
    const int rem = pos % (HO*WO);
    const int ho  = rem / WO;
    const int wo  = rem % WO;

    #pragma unroll
    for (int slab = 0; slab < 9; ++slab) {
        const int kh = slab / 3, kw = slab % 3;
        const float* src = x + (((b*H_IN + ho + kh)*W_IN + (wo + kw))*FIN)*DI;
        patch[slab*256 + tid] = src[tid];
    }
    __syncthreads();

    const float4* pv = (const float4*)patch;

    {
        const int fo0 = tid, fo1 = tid + 256;
        const int f0 = fo0 >> 4, o0 = fo0 & 15;
        const int f1 = fo1 >> 4, o1 = fo1 & 15;
        float acc0 = 0.f, acc1 = 0.f;
        for (int c = 0; c < C; ++c) {
            const float4 p0 = pv[c*2], p1 = pv[c*2+1];
            acc0 += dot8((const float4*)(Wt + ((f0*C + c)*DO + o0)*DI), p0, p1);
            acc1 += dot8((const float4*)(Wt + ((f1*C + c)*DO + o1)*DI), p0, p1);
        }
        cent[fo0] = acc0 * (1.f/32.f);
        cent[fo1] = acc1 * (1.f/32.f);
    }
    __syncthreads();

    if (tid < F) {
        float sn = 0.f;
        #pragma unroll
        for (int o = 0; o < DO; ++o) { float v = cent[tid*DO + o]; sn += v*v; }
        const float sc = (sn/(1.f + sn)) * rsqrtf(sn + EPS);
        #pragma unroll
        for (int o = 0; o < DO; ++o) out1[tid*DO + o] = cent[tid*DO + o] * sc;
    }
    __syncthreads();

    #pragma unroll 1
    for (int r = 0; r < (F*C)/256; ++r) {
        const int pp = tid + 256*r;
        const int f = pp / C, c = pp % C;
        const float4* wrow = (const float4*)(Wt + (f*C + c)*DO*DI);
        const float4 p0 = pv[c*2], p1 = pv[c*2+1];
        float a = 0.f;
        #pragma unroll
        for (int o = 0; o < DO; ++o) a += dot8(wrow + o*2, p0, p1) * out1[f*DO + o];
        agr[pp] = a;
    }
    __syncthreads();

    for (int c = tid; c < C; c += 256) {
        float m = -1e30f;
        #pragma unroll
        for (int f = 0; f < F; ++f) m = fmaxf(m, agr[f*C + c]);
        float s = 0.f;
        #pragma unroll
        for (int f = 0; f < F; ++f) {
            const float e = __expf(agr[f*C + c] - m);
            agr[f*C + c] = e; s += e;
        }
        const float inv = 1.f / s;
        #pragma unroll
        for (int f = 0; f < F; ++f) agr[f*C + c] *= inv;
    }
    __syncthreads();

    {
        const int fo0 = tid, fo1 = tid + 256;
        const int f0 = fo0 >> 4, o0 = fo0 & 15;
        const int f1 = fo1 >> 4, o1 = fo1 & 15;
        float acc0 = 0.f, acc1 = 0.f;
        for (int c = 0; c < C; ++c) {
            const float4 p0 = pv[c*2], p1 = pv[c*2+1];
            acc0 += agr[f0*C + c] * dot8((const float4*)(Wt + ((f0*C + c)*DO + o0)*DI), p0, p1);
            acc1 += agr[f1*C + c] * dot8((const float4*)(Wt + ((f1*C + c)*DO + o1)*DI), p0, p1);
        }
        cent[fo0] = acc0;
        cent[fo1] = acc1;
    }
    __syncthreads();

    if (tid < F) {
        float sn = 0.f;
        #pragma unroll
        for (int o = 0; o < DO; ++o) { float v = cent[tid*DO + o]; sn += v*v; }
        scale_s[tid] = (sn/(1.f + sn)) * rsqrtf(sn + EPS);
    }
    __syncthreads();

    out[pos*(F*DO) + tid]       = cent[tid]       * scale_s[tid >> 4];
    out[pos*(F*DO) + tid + 256] = cent[tid + 256] * scale_s[(tid >> 4) + 16];
}

extern "C" void kernel_launch(void* const* d_in, const int* in_sizes, int n_in,
                              void* d_out, int out_size, void* d_ws, size_t ws_size,
                              hipStream_t stream) {
    const float* x  = (const float*)d_in[0];
    const float* Wt = (const float*)d_in[1];
    float* out = (float*)d_out;

    if (ws_size >= W2H_BYTES + XH_BYTES + PART_BYTES + OUT1_BYTES) {
        unsigned short* W2h = (unsigned short*)d_ws;
        unsigned short* xh  = (unsigned short*)((char*)d_ws + W2H_BYTES);
        float* part1 = (float*)((char*)d_ws + W2H_BYTES + XH_BYTES);   // part2 aliases
        float* out1  = (float*)((char*)d_ws + W2H_BYTES + XH_BYTES + PART_BYTES);
        kernConv<<<(F*C*DO)/256 + XELE/4/256, 256, 0, stream>>>(Wt, W2h, x, xh); // 772
        kern1n<<<CH*(NPOS/8), 256, 0, stream>>>(xh, W2h, part1);       // 1152 blocks
        kernO<<<NPOS, 512, 0, stream>>>(part1, out1);                  // 576 blocks
        kern2n<<<CH*(NPOS/8), 256, 0, stream>>>(xh, W2h, out1, part1); // 1152 blocks
        kern3<<<NPOS/8, 256, 0, stream>>>(part1, out);                 // 72 blocks
    } else {
        capsule_kernel_f32<<<NPOS, 256, 0, stream>>>(x, Wt, out);
    }
}